// Round 1
// baseline (2762.563 us; speedup 1.0000x reference)
//
#include <hip/hip_runtime.h>
#include <hip/hip_bf16.h>

// GraphConvolution: out = segment_sum(vals[:,None] * support[cols], rows)
// N=100000 nodes, E=1600000 edges, F=128 features, fp32.
//
// Round 0: atomic scatter baseline.
//  - 32 threads per edge, each handles one float4 (4 features).
//  - unsafeAtomicAdd -> hardware global_atomic_add_f32 (no CAS loop).
//  - d_out zeroed via hipMemsetAsync (graph-capture safe).

#define D_FEAT 128
#define CHUNKS_PER_EDGE 32   // 128 floats / 4 per float4

__global__ void gc_scatter_kernel(const float* __restrict__ support,
                                  const float* __restrict__ vals,
                                  const int* __restrict__ rows,
                                  const int* __restrict__ cols,
                                  float* __restrict__ out,
                                  int n_edges) {
    unsigned int t = blockIdx.x * blockDim.x + threadIdx.x;
    unsigned int e = t >> 5;        // edge index
    unsigned int j = t & 31;        // float4 chunk within the feature vector
    if (e >= (unsigned int)n_edges) return;

    int r = rows[e];
    int c = cols[e];
    float v = vals[e];

    const float4* s4 = reinterpret_cast<const float4*>(support) +
                       (size_t)c * CHUNKS_PER_EDGE + j;
    float4 s = *s4;

    float* o = out + (size_t)r * D_FEAT + j * 4;
    unsafeAtomicAdd(o + 0, v * s.x);
    unsafeAtomicAdd(o + 1, v * s.y);
    unsafeAtomicAdd(o + 2, v * s.z);
    unsafeAtomicAdd(o + 3, v * s.w);
}

extern "C" void kernel_launch(void* const* d_in, const int* in_sizes, int n_in,
                              void* d_out, int out_size, void* d_ws, size_t ws_size,
                              hipStream_t stream) {
    const float* support = (const float*)d_in[0];
    const float* vals    = (const float*)d_in[1];
    const int*   rows    = (const int*)d_in[2];
    const int*   cols    = (const int*)d_in[3];
    float* out = (float*)d_out;

    int n_edges = in_sizes[1];

    // d_out is re-poisoned to 0xAA before every timed launch — zero it.
    hipMemsetAsync(d_out, 0, (size_t)out_size * sizeof(float), stream);

    unsigned int total_threads = (unsigned int)n_edges * CHUNKS_PER_EDGE;
    unsigned int block = 256;
    unsigned int grid = (total_threads + block - 1) / block;
    gc_scatter_kernel<<<grid, block, 0, stream>>>(support, vals, rows, cols,
                                                  out, n_edges);
}

// Round 2
// 401.511 us; speedup vs baseline: 6.8804x; 6.8804x over previous
//
#include <hip/hip_runtime.h>
#include <hip/hip_bf16.h>

// GraphConvolution: out = segment_sum(vals[:,None] * support[cols], rows)
// N=100000 nodes, E=1600000 edges, F=128 features, fp32.
//
// Round 1: CSR-build + register-accumulate gather (no float atomics).
//  R0 post-mortem: 205M f32 atomics caused WRITE_SIZE=3.2GB (16B HBM write
//  per 4B atomic). Fix: per-launch CSR build in d_ws, then one wave-slice
//  per row accumulates in registers and writes each output float exactly once.

#define D_FEAT 128
#define F4 32            // float4s per feature vector
#define SCAN_CHUNK 1024  // elements per scan block

// ---- 1. histogram: counts[r] = degree(r) ----
__global__ void hist_kernel(const int* __restrict__ rows,
                            int* __restrict__ counts, int n_edges) {
    int e = blockIdx.x * blockDim.x + threadIdx.x;
    if (e < n_edges) atomicAdd(&counts[rows[e]], 1);
}

// ---- 2a. per-block reduction of counts -> bsums[b] ----
__global__ void reduce_kernel(const int* __restrict__ counts,
                              int* __restrict__ bsums, int n) {
    __shared__ int wsum[16];
    int i = blockIdx.x * SCAN_CHUNK + threadIdx.x;
    int x = (i < n) ? counts[i] : 0;
    for (int o = 32; o > 0; o >>= 1) x += __shfl_down(x, o);
    if ((threadIdx.x & 63) == 0) wsum[threadIdx.x >> 6] = x;
    __syncthreads();
    if (threadIdx.x == 0) {
        int s = 0;
        #pragma unroll
        for (int w = 0; w < 16; ++w) s += wsum[w];
        bsums[blockIdx.x] = s;
    }
}

// ---- 2b. single-block exclusive scan of bsums (nblocks <= 1024) ----
__global__ void scan_bsums_kernel(int* __restrict__ bsums, int nblocks) {
    __shared__ int lds[1024];
    int tid = threadIdx.x;
    int x = (tid < nblocks) ? bsums[tid] : 0;
    lds[tid] = x;
    __syncthreads();
    for (int o = 1; o < 1024; o <<= 1) {
        int t = (tid >= o) ? lds[tid - o] : 0;
        __syncthreads();
        lds[tid] += t;
        __syncthreads();
    }
    if (tid < nblocks) bsums[tid] = lds[tid] - x;        // exclusive prefix
    if (tid == nblocks - 1) bsums[nblocks] = lds[tid];   // grand total
}

// ---- 2c. local scan + block prefix -> offsets[] and cursor[] ----
__global__ void scan_write_kernel(const int* __restrict__ counts,
                                  const int* __restrict__ bsums,
                                  int* __restrict__ offsets,
                                  int* __restrict__ cursor,
                                  int n, int nblocks) {
    __shared__ int wsum[16];
    int i = blockIdx.x * SCAN_CHUNK + threadIdx.x;
    int lane = threadIdx.x & 63;
    int wid  = threadIdx.x >> 6;
    int x = (i < n) ? counts[i] : 0;
    // wave-inclusive scan
    int incl = x;
    for (int o = 1; o < 64; o <<= 1) {
        int t = __shfl_up(incl, o);
        if (lane >= o) incl += t;
    }
    if (lane == 63) wsum[wid] = incl;
    __syncthreads();
    if (threadIdx.x < 16) {
        int v = wsum[threadIdx.x];
        for (int o = 1; o < 16; o <<= 1) {
            int t = __shfl_up(v, o);
            if ((int)threadIdx.x >= o) v += t;
        }
        wsum[threadIdx.x] = v;  // inclusive over wave sums
    }
    __syncthreads();
    int wprefix = (wid == 0) ? 0 : wsum[wid - 1];
    int excl = bsums[blockIdx.x] + wprefix + (incl - x);
    if (i < n) { offsets[i] = excl; cursor[i] = excl; }
    if (blockIdx.x == 0 && threadIdx.x == 0) offsets[n] = bsums[nblocks];
}

// ---- 3. bucket edges into (col, val) pairs in CSR order ----
__global__ void bucket_kernel(const int* __restrict__ rows,
                              const int* __restrict__ cols,
                              const float* __restrict__ vals,
                              int* __restrict__ cursor,
                              int2* __restrict__ pairs, int n_edges) {
    int e = blockIdx.x * blockDim.x + threadIdx.x;
    if (e >= n_edges) return;
    int r = rows[e];
    int pos = atomicAdd(&cursor[r], 1);
    int2 p;
    p.x = cols[e];
    p.y = __float_as_int(vals[e]);
    pairs[pos] = p;
}

// ---- 4. gather: 32 lanes per row, register accumulate, single write ----
__global__ void gather_kernel(const float4* __restrict__ support4,
                              const int* __restrict__ offsets,
                              const int2* __restrict__ pairs,
                              float4* __restrict__ out4, int n_nodes) {
    unsigned int t = blockIdx.x * blockDim.x + threadIdx.x;
    unsigned int row = t >> 5;
    unsigned int j = t & 31;
    if (row >= (unsigned int)n_nodes) return;
    int beg = offsets[row];
    int end = offsets[row + 1];
    float4 acc = {0.f, 0.f, 0.f, 0.f};
    for (int k = beg; k < end; ++k) {
        int2 p = pairs[k];
        float v = __int_as_float(p.y);
        float4 s = support4[(size_t)p.x * F4 + j];
        acc.x += v * s.x;
        acc.y += v * s.y;
        acc.z += v * s.z;
        acc.w += v * s.w;
    }
    out4[(size_t)row * F4 + j] = acc;
}

// ---- fallback (R0 atomic scatter) if workspace is too small ----
__global__ void gc_scatter_kernel(const float* __restrict__ support,
                                  const float* __restrict__ vals,
                                  const int* __restrict__ rows,
                                  const int* __restrict__ cols,
                                  float* __restrict__ out, int n_edges) {
    unsigned int t = blockIdx.x * blockDim.x + threadIdx.x;
    unsigned int e = t >> 5;
    unsigned int j = t & 31;
    if (e >= (unsigned int)n_edges) return;
    int r = rows[e];
    int c = cols[e];
    float v = vals[e];
    const float4* s4 = reinterpret_cast<const float4*>(support) + (size_t)c * F4 + j;
    float4 s = *s4;
    float* o = out + (size_t)r * D_FEAT + j * 4;
    unsafeAtomicAdd(o + 0, v * s.x);
    unsafeAtomicAdd(o + 1, v * s.y);
    unsafeAtomicAdd(o + 2, v * s.z);
    unsafeAtomicAdd(o + 3, v * s.w);
}

extern "C" void kernel_launch(void* const* d_in, const int* in_sizes, int n_in,
                              void* d_out, int out_size, void* d_ws, size_t ws_size,
                              hipStream_t stream) {
    const float* support = (const float*)d_in[0];
    const float* vals    = (const float*)d_in[1];
    const int*   rows    = (const int*)d_in[2];
    const int*   cols    = (const int*)d_in[3];
    float* out = (float*)d_out;

    int E = in_sizes[1];
    int N = in_sizes[0] / D_FEAT;
    int nblocks = (N + SCAN_CHUNK - 1) / SCAN_CHUNK;  // 98 for N=100000

    // workspace carve-up (256B aligned)
    char* ws = (char*)d_ws;
    size_t cur = 0;
    auto carve = [&](size_t bytes) -> void* {
        void* p = ws + cur;
        cur += (bytes + 255) & ~(size_t)255;
        return p;
    };
    int*  offsets = (int*)carve((size_t)(N + 1) * 4);
    int*  counts  = (int*)carve((size_t)N * 4);
    int*  cursor  = (int*)carve((size_t)N * 4);
    int*  bsums   = (int*)carve((size_t)(nblocks + 1) * 4);
    int2* pairs   = (int2*)carve((size_t)E * 8);

    if (cur > ws_size || nblocks > 1024) {
        // fallback: R0 atomic scatter
        hipMemsetAsync(d_out, 0, (size_t)out_size * sizeof(float), stream);
        unsigned int total = (unsigned int)E * F4;
        gc_scatter_kernel<<<(total + 255) / 256, 256, 0, stream>>>(
            support, vals, rows, cols, out, E);
        return;
    }

    hipMemsetAsync(counts, 0, (size_t)N * 4, stream);
    hist_kernel<<<(E + 255) / 256, 256, 0, stream>>>(rows, counts, E);
    reduce_kernel<<<nblocks, SCAN_CHUNK, 0, stream>>>(counts, bsums, N);
    scan_bsums_kernel<<<1, 1024, 0, stream>>>(bsums, nblocks);
    scan_write_kernel<<<nblocks, SCAN_CHUNK, 0, stream>>>(counts, bsums, offsets,
                                                          cursor, N, nblocks);
    bucket_kernel<<<(E + 255) / 256, 256, 0, stream>>>(rows, cols, vals, cursor,
                                                       pairs, E);

    unsigned int gthreads = (unsigned int)N * F4;
    gather_kernel<<<(gthreads + 255) / 256, 256, 0, stream>>>(
        (const float4*)support, offsets, pairs, (float4*)out, N);
}

// Round 4
// 291.034 us; speedup vs baseline: 9.4922x; 1.3796x over previous
//
#include <hip/hip_runtime.h>
#include <hip/hip_bf16.h>

// GraphConvolution: out = segment_sum(vals[:,None] * support[cols], rows)
// N=100000 nodes, E=1600000 edges, F=128 features, fp32.
//
// Round 3: same as R2 (padded-bucket build + shfl-broadcast gather), with the
// nontemporal store fixed to use a native clang ext_vector_type (the builtin
// rejects HIP_vector_type classes).

#define D_FEAT 128
#define F4 32            // float4s per feature vector
#define STRIDE 64        // padded slots per row (Poisson(16): P(deg>64) ~ 0)
#define OVF_CAP 8192     // overflow insurance
#define SCAN_CHUNK 1024

typedef float vfloat4 __attribute__((ext_vector_type(4)));

// ======================= primary path (padded buckets) =======================

__global__ void bucket_padded_kernel(const int* __restrict__ rows,
                                     const int* __restrict__ cols,
                                     const float* __restrict__ vals,
                                     int* __restrict__ cursor,
                                     int* __restrict__ ovf_count,
                                     int2* __restrict__ pairs,
                                     int4* __restrict__ ovf,
                                     int n_edges) {
    int e = blockIdx.x * blockDim.x + threadIdx.x;
    if (e >= n_edges) return;
    int r = rows[e];
    int slot = atomicAdd(&cursor[r], 1);
    int2 p;
    p.x = cols[e];
    p.y = __float_as_int(vals[e]);
    if (slot < STRIDE) {
        pairs[(size_t)r * STRIDE + slot] = p;
    } else {
        int o = atomicAdd(ovf_count, 1);
        if (o < OVF_CAP) {
            int4 q; q.x = r; q.y = p.x; q.z = p.y; q.w = 0;
            ovf[o] = q;
        }
    }
}

__global__ void gather_padded_kernel(const float4* __restrict__ support4,
                                     const int* __restrict__ cursor,
                                     const int2* __restrict__ pairs,
                                     float4* __restrict__ out4, int n_nodes) {
    unsigned int t = blockIdx.x * blockDim.x + threadIdx.x;
    unsigned int row = t >> 5;
    unsigned int j = t & 31;
    if (row >= (unsigned int)n_nodes) return;
    int deg = cursor[row];
    if (deg > STRIDE) deg = STRIDE;

    // Cooperative preload of this row's pair list (coalesced, predicated),
    // then broadcast through registers — keeps pair reads off the critical path.
    const int2* pr = pairs + (size_t)row * STRIDE;
    int2 z = {0, 0};
    int2 p0 = ((int)j < deg) ? pr[j] : z;
    int2 p1 = ((int)(j + 32) < deg) ? pr[j + 32] : z;
    int   c0 = p0.x;  float v0 = __int_as_float(p0.y);
    int   c1 = p1.x;  float v1 = __int_as_float(p1.y);

    float4 a0 = {0,0,0,0}, a1 = {0,0,0,0}, a2 = {0,0,0,0}, a3 = {0,0,0,0};
    int k = 0;
    for (; k + 4 <= deg; k += 4) {
        int   cA = __shfl((k+0) < 32 ? c0 : c1, (k+0) & 31, 32);
        int   cB = __shfl((k+1) < 32 ? c0 : c1, (k+1) & 31, 32);
        int   cC = __shfl((k+2) < 32 ? c0 : c1, (k+2) & 31, 32);
        int   cD = __shfl((k+3) < 32 ? c0 : c1, (k+3) & 31, 32);
        float vA = __shfl((k+0) < 32 ? v0 : v1, (k+0) & 31, 32);
        float vB = __shfl((k+1) < 32 ? v0 : v1, (k+1) & 31, 32);
        float vC = __shfl((k+2) < 32 ? v0 : v1, (k+2) & 31, 32);
        float vD = __shfl((k+3) < 32 ? v0 : v1, (k+3) & 31, 32);
        float4 sA = support4[(size_t)cA * F4 + j];
        float4 sB = support4[(size_t)cB * F4 + j];
        float4 sC = support4[(size_t)cC * F4 + j];
        float4 sD = support4[(size_t)cD * F4 + j];
        a0.x += vA * sA.x; a0.y += vA * sA.y; a0.z += vA * sA.z; a0.w += vA * sA.w;
        a1.x += vB * sB.x; a1.y += vB * sB.y; a1.z += vB * sB.z; a1.w += vB * sB.w;
        a2.x += vC * sC.x; a2.y += vC * sC.y; a2.z += vC * sC.z; a2.w += vC * sC.w;
        a3.x += vD * sD.x; a3.y += vD * sD.y; a3.z += vD * sD.z; a3.w += vD * sD.w;
    }
    for (; k < deg; ++k) {
        int   c = __shfl(k < 32 ? c0 : c1, k & 31, 32);
        float v = __shfl(k < 32 ? v0 : v1, k & 31, 32);
        float4 s = support4[(size_t)c * F4 + j];
        a0.x += v * s.x; a0.y += v * s.y; a0.z += v * s.z; a0.w += v * s.w;
    }
    vfloat4 acc;
    acc.x = (a0.x + a1.x) + (a2.x + a3.x);
    acc.y = (a0.y + a1.y) + (a2.y + a3.y);
    acc.z = (a0.z + a1.z) + (a2.z + a3.z);
    acc.w = (a0.w + a1.w) + (a2.w + a3.w);
    __builtin_nontemporal_store(acc, (vfloat4*)&out4[(size_t)row * F4 + j]);
}

__global__ void ovf_scatter_kernel(const float* __restrict__ support,
                                   const int4* __restrict__ ovf,
                                   const int* __restrict__ ovf_count,
                                   float* __restrict__ out) {
    int t = blockIdx.x * blockDim.x + threadIdx.x;
    int i = t >> 5;
    int j = t & 31;
    int cnt = *ovf_count;
    if (cnt > OVF_CAP) cnt = OVF_CAP;
    if (i >= cnt) return;
    int4 q = ovf[i];
    float v = __int_as_float(q.z);
    const float4* s4 = (const float4*)support + (size_t)q.y * F4 + j;
    float4 s = *s4;
    float* o = out + (size_t)q.x * D_FEAT + j * 4;
    unsafeAtomicAdd(o + 0, v * s.x);
    unsafeAtomicAdd(o + 1, v * s.y);
    unsafeAtomicAdd(o + 2, v * s.z);
    unsafeAtomicAdd(o + 3, v * s.w);
}

// ==================== fallback 1: exact CSR (R1 pipeline) ====================

__global__ void hist_kernel(const int* __restrict__ rows,
                            int* __restrict__ counts, int n_edges) {
    int e = blockIdx.x * blockDim.x + threadIdx.x;
    if (e < n_edges) atomicAdd(&counts[rows[e]], 1);
}

__global__ void reduce_kernel(const int* __restrict__ counts,
                              int* __restrict__ bsums, int n) {
    __shared__ int wsum[16];
    int i = blockIdx.x * SCAN_CHUNK + threadIdx.x;
    int x = (i < n) ? counts[i] : 0;
    for (int o = 32; o > 0; o >>= 1) x += __shfl_down(x, o);
    if ((threadIdx.x & 63) == 0) wsum[threadIdx.x >> 6] = x;
    __syncthreads();
    if (threadIdx.x == 0) {
        int s = 0;
        #pragma unroll
        for (int w = 0; w < 16; ++w) s += wsum[w];
        bsums[blockIdx.x] = s;
    }
}

__global__ void scan_bsums_kernel(int* __restrict__ bsums, int nblocks) {
    __shared__ int lds[1024];
    int tid = threadIdx.x;
    int x = (tid < nblocks) ? bsums[tid] : 0;
    lds[tid] = x;
    __syncthreads();
    for (int o = 1; o < 1024; o <<= 1) {
        int t = (tid >= o) ? lds[tid - o] : 0;
        __syncthreads();
        lds[tid] += t;
        __syncthreads();
    }
    if (tid < nblocks) bsums[tid] = lds[tid] - x;
    if (tid == nblocks - 1) bsums[nblocks] = lds[tid];
}

__global__ void scan_write_kernel(const int* __restrict__ counts,
                                  const int* __restrict__ bsums,
                                  int* __restrict__ offsets,
                                  int* __restrict__ cursor,
                                  int n, int nblocks) {
    __shared__ int wsum[16];
    int i = blockIdx.x * SCAN_CHUNK + threadIdx.x;
    int lane = threadIdx.x & 63;
    int wid  = threadIdx.x >> 6;
    int x = (i < n) ? counts[i] : 0;
    int incl = x;
    for (int o = 1; o < 64; o <<= 1) {
        int t = __shfl_up(incl, o);
        if (lane >= o) incl += t;
    }
    if (lane == 63) wsum[wid] = incl;
    __syncthreads();
    if (threadIdx.x < 16) {
        int v = wsum[threadIdx.x];
        for (int o = 1; o < 16; o <<= 1) {
            int t = __shfl_up(v, o);
            if ((int)threadIdx.x >= o) v += t;
        }
        wsum[threadIdx.x] = v;
    }
    __syncthreads();
    int wprefix = (wid == 0) ? 0 : wsum[wid - 1];
    int excl = bsums[blockIdx.x] + wprefix + (incl - x);
    if (i < n) { offsets[i] = excl; cursor[i] = excl; }
    if (blockIdx.x == 0 && threadIdx.x == 0) offsets[n] = bsums[nblocks];
}

__global__ void bucket_kernel(const int* __restrict__ rows,
                              const int* __restrict__ cols,
                              const float* __restrict__ vals,
                              int* __restrict__ cursor,
                              int2* __restrict__ pairs, int n_edges) {
    int e = blockIdx.x * blockDim.x + threadIdx.x;
    if (e >= n_edges) return;
    int r = rows[e];
    int pos = atomicAdd(&cursor[r], 1);
    int2 p;
    p.x = cols[e];
    p.y = __float_as_int(vals[e]);
    pairs[pos] = p;
}

__global__ void gather_kernel(const float4* __restrict__ support4,
                              const int* __restrict__ offsets,
                              const int2* __restrict__ pairs,
                              float4* __restrict__ out4, int n_nodes) {
    unsigned int t = blockIdx.x * blockDim.x + threadIdx.x;
    unsigned int row = t >> 5;
    unsigned int j = t & 31;
    if (row >= (unsigned int)n_nodes) return;
    int beg = offsets[row];
    int end = offsets[row + 1];
    float4 acc = {0.f, 0.f, 0.f, 0.f};
    for (int k = beg; k < end; ++k) {
        int2 p = pairs[k];
        float v = __int_as_float(p.y);
        float4 s = support4[(size_t)p.x * F4 + j];
        acc.x += v * s.x;
        acc.y += v * s.y;
        acc.z += v * s.z;
        acc.w += v * s.w;
    }
    out4[(size_t)row * F4 + j] = acc;
}

// ==================== fallback 2: atomic scatter (R0) ====================

__global__ void gc_scatter_kernel(const float* __restrict__ support,
                                  const float* __restrict__ vals,
                                  const int* __restrict__ rows,
                                  const int* __restrict__ cols,
                                  float* __restrict__ out, int n_edges) {
    unsigned int t = blockIdx.x * blockDim.x + threadIdx.x;
    unsigned int e = t >> 5;
    unsigned int j = t & 31;
    if (e >= (unsigned int)n_edges) return;
    int r = rows[e];
    int c = cols[e];
    float v = vals[e];
    const float4* s4 = reinterpret_cast<const float4*>(support) + (size_t)c * F4 + j;
    float4 s = *s4;
    float* o = out + (size_t)r * D_FEAT + j * 4;
    unsafeAtomicAdd(o + 0, v * s.x);
    unsafeAtomicAdd(o + 1, v * s.y);
    unsafeAtomicAdd(o + 2, v * s.z);
    unsafeAtomicAdd(o + 3, v * s.w);
}

// ============================ launch ============================

extern "C" void kernel_launch(void* const* d_in, const int* in_sizes, int n_in,
                              void* d_out, int out_size, void* d_ws, size_t ws_size,
                              hipStream_t stream) {
    const float* support = (const float*)d_in[0];
    const float* vals    = (const float*)d_in[1];
    const int*   rows    = (const int*)d_in[2];
    const int*   cols    = (const int*)d_in[3];
    float* out = (float*)d_out;

    int E = in_sizes[1];
    int N = in_sizes[0] / D_FEAT;

    char* ws = (char*)d_ws;
    size_t cur = 0;
    auto carve = [&](size_t bytes) -> void* {
        void* p = ws + cur;
        cur += (bytes + 255) & ~(size_t)255;
        return p;
    };

    // ---- primary: padded buckets ----
    {
        size_t save = cur;
        int*  cursor = (int*)carve((size_t)(N + 1) * 4);  // [N] = ovf_count
        int2* pairs  = (int2*)carve((size_t)N * STRIDE * 8);
        int4* ovf    = (int4*)carve((size_t)OVF_CAP * 16);
        if (cur <= ws_size) {
            int* ovf_count = cursor + N;
            (void)hipMemsetAsync(cursor, 0, (size_t)(N + 1) * 4, stream);
            bucket_padded_kernel<<<(E + 255) / 256, 256, 0, stream>>>(
                rows, cols, vals, cursor, ovf_count, pairs, ovf, E);
            unsigned int gthreads = (unsigned int)N * F4;
            gather_padded_kernel<<<(gthreads + 255) / 256, 256, 0, stream>>>(
                (const float4*)support, cursor, pairs, (float4*)out, N);
            ovf_scatter_kernel<<<(OVF_CAP * 32) / 256, 256, 0, stream>>>(
                support, ovf, ovf_count, out);
            return;
        }
        cur = save;
    }

    // ---- fallback 1: exact CSR ----
    {
        int nblocks = (N + SCAN_CHUNK - 1) / SCAN_CHUNK;
        size_t save = cur;
        int*  offsets = (int*)carve((size_t)(N + 1) * 4);
        int*  counts  = (int*)carve((size_t)N * 4);
        int*  cursor  = (int*)carve((size_t)N * 4);
        int*  bsums   = (int*)carve((size_t)(nblocks + 1) * 4);
        int2* pairs   = (int2*)carve((size_t)E * 8);
        if (cur <= ws_size && nblocks <= 1024) {
            (void)hipMemsetAsync(counts, 0, (size_t)N * 4, stream);
            hist_kernel<<<(E + 255) / 256, 256, 0, stream>>>(rows, counts, E);
            reduce_kernel<<<nblocks, SCAN_CHUNK, 0, stream>>>(counts, bsums, N);
            scan_bsums_kernel<<<1, 1024, 0, stream>>>(bsums, nblocks);
            scan_write_kernel<<<nblocks, SCAN_CHUNK, 0, stream>>>(
                counts, bsums, offsets, cursor, N, nblocks);
            bucket_kernel<<<(E + 255) / 256, 256, 0, stream>>>(
                rows, cols, vals, cursor, pairs, E);
            unsigned int gthreads = (unsigned int)N * F4;
            gather_kernel<<<(gthreads + 255) / 256, 256, 0, stream>>>(
                (const float4*)support, offsets, pairs, (float4*)out, N);
            return;
        }
        cur = save;
    }

    // ---- fallback 2: atomic scatter ----
    (void)hipMemsetAsync(d_out, 0, (size_t)out_size * sizeof(float), stream);
    unsigned int total = (unsigned int)E * F4;
    gc_scatter_kernel<<<(total + 255) / 256, 256, 0, stream>>>(
        support, vals, rows, cols, out, E);
}